// Round 1
// baseline (294.239 us; speedup 1.0000x reference)
//
#include <hip/hip_runtime.h>
#include <hip/hip_bf16.h>
#include <math.h>

// Problem constants
#define NB    4096
#define DH    784
#define KX    800            // 784 padded to 25*32 for BK=32 MFMA loop
#define NSR   5
#define NNEG  (NB*NSR)       // 20480
#define NTOT  (NB + NNEG)    // 24576

#define A_CONST 1.576943f
#define PEXP    1.7901216f   // 2*B_PARAM
#define EPS_C   1.0e-4f
#define ALPHA_C 0.9296875f   // BATCH_COUNT=500: beta=0.5*(1-500/800)^2=0.0703125
#define BETA_C  0.0703125f

typedef __hip_bfloat16 bf16;
typedef short bf16x8 __attribute__((ext_vector_type(8)));
typedef float f32x4  __attribute__((ext_vector_type(4)));

// Workspace layout (bytes)
#define WS_XBF   0                       // 4096*800*2 = 6553600
#define WS_EBF   6553600                 // 4096*32*2  = 262144
#define WS_SQX   6815744                 // 4096*4     = 16384
#define WS_SQE   6832128                 // 4096*4     = 16384
#define WS_STATS 6848512                 // 4096*5*4   = 81920
#define WS_USUM  6930432                 // 4

__device__ __forceinline__ void gl2lds16(const bf16* g, bf16* l) {
    __builtin_amdgcn_global_load_lds(
        (const __attribute__((address_space(1))) unsigned int*)g,
        (__attribute__((address_space(3))) unsigned int*)l,
        16, 0, 0);
}

// ---- prep: X (4096x784 f32) -> bf16 padded 4096x800, and row sq-norms (f32)
__global__ void prep_x(const float* __restrict__ X, bf16* __restrict__ Xbf,
                       float* __restrict__ sqx) {
    const int row = blockIdx.x;
    const float* xr = X + (size_t)row * DH;
    bf16* xb = Xbf + (size_t)row * KX;
    float s = 0.f;
    for (int c = threadIdx.x; c < KX; c += 128) {
        float v = (c < DH) ? xr[c] : 0.f;
        xb[c] = __float2bfloat16(v);
        s += v * v;
    }
    #pragma unroll
    for (int off = 32; off; off >>= 1) s += __shfl_down(s, off, 64);
    __shared__ float ps[2];
    if ((threadIdx.x & 63) == 0) ps[threadIdx.x >> 6] = s;
    __syncthreads();
    if (threadIdx.x == 0) sqx[row] = ps[0] + ps[1];
}

// ---- prep: e_to (cols 0..15 of embed) -> bf16 4096x32 (upper 16 zero), sq-norms
__global__ void prep_e(const float* __restrict__ emb, bf16* __restrict__ Ebf,
                       float* __restrict__ sqe) {
    const int r = blockIdx.x * blockDim.x + threadIdx.x;
    if (r >= NB) return;
    const float* er = emb + (size_t)r * 32;
    bf16* eb = Ebf + (size_t)r * 32;
    float s = 0.f;
    #pragma unroll
    for (int c = 0; c < 16; ++c) {
        float v = er[c];
        eb[c] = __float2bfloat16(v);
        eb[16 + c] = __float2bfloat16(0.f);
        s += v * v;
    }
    sqe[r] = s;
}

// ---- UMAP CE loss: sum over 4096 pos + 20480 neg pairs
__global__ void umap_kernel(const float* __restrict__ emb, const int* __restrict__ perm,
                            float* __restrict__ usum) {
    const int t = blockIdx.x * 256 + threadIdx.x;
    float val = 0.f;
    if (t < NB) {
        const float* a = emb + (size_t)t * 32;
        float d2 = 0.f;
        #pragma unroll
        for (int c = 0; c < 16; ++c) { float df = a[c] - a[16 + c]; d2 += df * df; }
        float d = sqrtf(d2);
        float p = 1.f / (1.f + A_CONST * powf(d, PEXP));
        val = -logf(fminf(fmaxf(p, EPS_C), 1.f));
    } else if (t < NTOT) {
        const int k = t - NB;
        const int ti = k / 5;
        const int fi = perm[k] / 5;
        const float* a = emb + (size_t)ti * 32;
        const float* b = emb + (size_t)fi * 32 + 16;
        float d2 = 0.f;
        #pragma unroll
        for (int c = 0; c < 16; ++c) { float df = a[c] - b[c]; d2 += df * df; }
        float d = sqrtf(d2);
        float p = 1.f / (1.f + A_CONST * powf(d, PEXP));
        val = -logf(fminf(fmaxf(1.f - p, EPS_C), 1.f));
    }
    #pragma unroll
    for (int off = 32; off; off >>= 1) val += __shfl_down(val, off, 64);
    __shared__ float ps[4];
    if ((threadIdx.x & 63) == 0) ps[threadIdx.x >> 6] = val;
    __syncthreads();
    if (threadIdx.x == 0) atomicAdd(usum, ps[0] + ps[1] + ps[2] + ps[3]);
}

// ---- main: 128x128 tile dual-gram (X-gram K=800, E-gram K=32) + fused stats epilogue
__global__ __launch_bounds__(256) void gram_kernel(
    const bf16* __restrict__ Xbf, const bf16* __restrict__ Ebf,
    const float* __restrict__ sqx, const float* __restrict__ sqe,
    float* __restrict__ stats) {
    __shared__ bf16 As[128 * 32];   // 8 KB
    __shared__ bf16 Bs[128 * 32];   // 8 KB
    __shared__ float sqxs[256];     // [0..127]=i rows, [128..255]=j cols
    __shared__ float sqes[256];

    const int i0 = blockIdx.y * 128;
    const int j0 = blockIdx.x * 128;
    const int tid  = threadIdx.x;
    const int wave = tid >> 6;
    const int lane = tid & 63;
    const int wy = wave >> 1, wx = wave & 1;
    const int quad = lane >> 4, l15 = lane & 15;

    f32x4 acc[4][4], accE[4][4];
    #pragma unroll
    for (int a = 0; a < 4; ++a)
        #pragma unroll
        for (int b = 0; b < 4; ++b) {
            acc[a][b]  = (f32x4){0.f, 0.f, 0.f, 0.f};
            accE[a][b] = (f32x4){0.f, 0.f, 0.f, 0.f};
        }

    // staging geometry: 8 chunks of 16 rows; wave stages chunks {2w, 2w+1};
    // lane L: row chunk*16 + (L>>2), 16B segment (L&3) within the 64B row-chunk.
    const int c0  = wave * 2;
    const int rA  = lane >> 2;
    const int seg = (lane & 3) * 8;

    for (int kk = 0; kk < KX; kk += 32) {
        __syncthreads();
        #pragma unroll
        for (int cc = 0; cc < 2; ++cc) {
            const int c = c0 + cc;
            gl2lds16(Xbf + (size_t)(i0 + c * 16 + rA) * KX + kk + seg, As + c * 512);
            gl2lds16(Xbf + (size_t)(j0 + c * 16 + rA) * KX + kk + seg, Bs + c * 512);
        }
        __syncthreads();
        bf16x8 af[4], bfr[4];
        #pragma unroll
        for (int mi = 0; mi < 4; ++mi)
            af[mi] = *(const bf16x8*)&As[(wy * 64 + mi * 16 + l15) * 32 + quad * 8];
        #pragma unroll
        for (int ni = 0; ni < 4; ++ni)
            bfr[ni] = *(const bf16x8*)&Bs[(wx * 64 + ni * 16 + l15) * 32 + quad * 8];
        #pragma unroll
        for (int mi = 0; mi < 4; ++mi)
            #pragma unroll
            for (int ni = 0; ni < 4; ++ni)
                acc[mi][ni] = __builtin_amdgcn_mfma_f32_16x16x32_bf16(
                    af[mi], bfr[ni], acc[mi][ni], 0, 0, 0);
    }

    // one extra K-iter for the low-dim (e_to) gram; rows are 64B = same geometry
    __syncthreads();
    #pragma unroll
    for (int cc = 0; cc < 2; ++cc) {
        const int c = c0 + cc;
        gl2lds16(Ebf + (size_t)(i0 + c * 16 + rA) * 32 + seg, As + c * 512);
        gl2lds16(Ebf + (size_t)(j0 + c * 16 + rA) * 32 + seg, Bs + c * 512);
    }
    if (tid < 128) {
        sqxs[tid] = sqx[i0 + tid]; sqxs[128 + tid] = sqx[j0 + tid];
        sqes[tid] = sqe[i0 + tid]; sqes[128 + tid] = sqe[j0 + tid];
    }
    __syncthreads();
    {
        bf16x8 af[4], bfr[4];
        #pragma unroll
        for (int mi = 0; mi < 4; ++mi)
            af[mi] = *(const bf16x8*)&As[(wy * 64 + mi * 16 + l15) * 32 + quad * 8];
        #pragma unroll
        for (int ni = 0; ni < 4; ++ni)
            bfr[ni] = *(const bf16x8*)&Bs[(wx * 64 + ni * 16 + l15) * 32 + quad * 8];
        #pragma unroll
        for (int mi = 0; mi < 4; ++mi)
            #pragma unroll
            for (int ni = 0; ni < 4; ++ni)
                accE[mi][ni] = __builtin_amdgcn_mfma_f32_16x16x32_bf16(
                    af[mi], bfr[ni], accE[mi][ni], 0, 0, 0);
    }

    // Epilogue: H = high dist, L = low dist; per-row partial stats -> atomics.
    // C/D layout: col = lane&15, row = quad*4 + reg  [verified m89/m91]
    #pragma unroll
    for (int mi = 0; mi < 4; ++mi) {
        const int ilocb = wy * 64 + mi * 16 + quad * 4;
        float sH[4] = {0,0,0,0}, sH2[4] = {0,0,0,0}, sL[4] = {0,0,0,0},
              sL2[4] = {0,0,0,0}, sHL[4] = {0,0,0,0};
        #pragma unroll
        for (int ni = 0; ni < 4; ++ni) {
            const int jloc = wx * 64 + ni * 16 + l15;
            const int j = j0 + jloc;
            const float sqxj = sqxs[128 + jloc];
            const float sqej = sqes[128 + jloc];
            #pragma unroll
            for (int r = 0; r < 4; ++r) {
                const int iloc = ilocb + r;
                const int i = i0 + iloc;
                float H, L;
                if (i == j) { H = 0.f; L = 0.f; }
                else {
                    float d2  = sqxs[iloc] + sqxj - 2.0f * acc[mi][ni][r];
                    H = sqrtf(fmaxf(d2, 0.f));
                    float d2e = sqes[iloc] + sqej - 2.0f * accE[mi][ni][r];
                    L = sqrtf(fmaxf(d2e, 0.f));
                }
                sH[r] += H; sH2[r] += H * H; sL[r] += L; sL2[r] += L * L; sHL[r] += H * L;
            }
        }
        #pragma unroll
        for (int r = 0; r < 4; ++r) {
            float v0 = sH[r], v1 = sH2[r], v2 = sL[r], v3 = sL2[r], v4 = sHL[r];
            #pragma unroll
            for (int off = 1; off < 16; off <<= 1) {  // reduce across the 16-lane quad
                v0 += __shfl_xor(v0, off, 64);
                v1 += __shfl_xor(v1, off, 64);
                v2 += __shfl_xor(v2, off, 64);
                v3 += __shfl_xor(v3, off, 64);
                v4 += __shfl_xor(v4, off, 64);
            }
            if (l15 == 0) {
                const int i = i0 + ilocb + r;
                atomicAdd(&stats[i * 5 + 0], v0);
                atomicAdd(&stats[i * 5 + 1], v1);
                atomicAdd(&stats[i * 5 + 2], v2);
                atomicAdd(&stats[i * 5 + 3], v3);
                atomicAdd(&stats[i * 5 + 4], v4);
            }
        }
    }
}

// ---- final: per-row correlation from stats, combine with UMAP loss
__global__ void finish_kernel(const float* __restrict__ stats, const float* __restrict__ usum,
                              float* __restrict__ out) {
    float local = 0.f;
    const float invN = 1.0f / (float)NB;
    for (int r = threadIdx.x; r < NB; r += 256) {
        float sh  = stats[r * 5 + 0];
        float sh2 = stats[r * 5 + 1];
        float sl  = stats[r * 5 + 2];
        float sl2 = stats[r * 5 + 3];
        float shl = stats[r * 5 + 4];
        float num = shl - sh * sl * invN;
        float vh  = fmaxf(sh2 - sh * sh * invN, 0.f);
        float vl  = fmaxf(sl2 - sl * sl * invN, 0.f);
        float den = sqrtf(vh) * sqrtf(vl);
        local += num / den;
    }
    #pragma unroll
    for (int off = 32; off; off >>= 1) local += __shfl_down(local, off, 64);
    __shared__ float ps[4];
    if ((threadIdx.x & 63) == 0) ps[threadIdx.x >> 6] = local;
    __syncthreads();
    if (threadIdx.x == 0) {
        float corr = (ps[0] + ps[1] + ps[2] + ps[3]) * invN;
        float loss_g = -corr;
        float loss_u = usum[0] / (float)NTOT;
        out[0] = ALPHA_C * loss_u + BETA_C * loss_g;
    }
}

extern "C" void kernel_launch(void* const* d_in, const int* in_sizes, int n_in,
                              void* d_out, int out_size, void* d_ws, size_t ws_size,
                              hipStream_t stream) {
    const float* emb  = (const float*)d_in[0];   // (4096, 32) f32
    const float* ph   = (const float*)d_in[1];   // (4096, 784) f32
    const int*   perm = (const int*)d_in[2];     // (20480,) i32
    float* out = (float*)d_out;

    char* ws = (char*)d_ws;
    bf16*  Xbf   = (bf16*) (ws + WS_XBF);
    bf16*  Ebf   = (bf16*) (ws + WS_EBF);
    float* sqx   = (float*)(ws + WS_SQX);
    float* sqe   = (float*)(ws + WS_SQE);
    float* stats = (float*)(ws + WS_STATS);
    float* usum  = (float*)(ws + WS_USUM);

    // zero stats (4096*5 f32) + usum (1 f32); ws is poisoned 0xAA each call
    hipMemsetAsync(ws + WS_STATS, 0, 5 * NB * 4 + 4, stream);

    prep_x<<<NB, 128, 0, stream>>>(ph, Xbf, sqx);
    prep_e<<<NB / 256, 256, 0, stream>>>(emb, Ebf, sqe);
    umap_kernel<<<NTOT / 256, 256, 0, stream>>>(emb, perm, usum);
    gram_kernel<<<dim3(32, 32), 256, 0, stream>>>(Xbf, Ebf, sqx, sqe, stats);
    finish_kernel<<<1, 256, 0, stream>>>(stats, usum, out);
}

// Round 2
// 160.742 us; speedup vs baseline: 1.8305x; 1.8305x over previous
//
#include <hip/hip_runtime.h>
#include <hip/hip_bf16.h>
#include <math.h>

// Problem constants
#define NB    4096
#define DH    784
#define KX    800            // 784 padded to 25*32 for BK=32 MFMA loop
#define NSR   5
#define NNEG  (NB*NSR)       // 20480
#define NTOT  (NB + NNEG)    // 24576

#define A_CONST 1.576943f
#define PEXP    1.7901216f   // 2*B_PARAM
#define EPS_C   1.0e-4f
#define ALPHA_C 0.9296875f   // BATCH_COUNT=500: beta=0.5*(1-500/800)^2=0.0703125
#define BETA_C  0.0703125f

#define NSLOT 64             // 32 j-blocks * 2 wx-waves
#define SLAB  (NB * NSLOT)   // elements per stat component = 262144

typedef __hip_bfloat16 bf16;
typedef short bf16x8 __attribute__((ext_vector_type(8)));
typedef float f32x4  __attribute__((ext_vector_type(4)));

// Workspace layout (bytes)
#define WS_XBF    0                      // 4096*800*2 = 6553600
#define WS_EBF    6553600                // 4096*32*2  = 262144
#define WS_SQX    6815744                // 4096*4     = 16384
#define WS_SQE    6832128                // 4096*4     = 16384
#define WS_STATSP 6848512                // 5*262144*4 = 5242880
#define WS_UPART  12091392               // 96*4       = 384
#define WS_CPART  12091776               // 16*4       = 64

__device__ __forceinline__ void gl2lds16(const bf16* g, bf16* l) {
    __builtin_amdgcn_global_load_lds(
        (const __attribute__((address_space(1))) unsigned int*)g,
        (__attribute__((address_space(3))) unsigned int*)l,
        16, 0, 0);
}

// ---- prep: X (4096x784 f32) -> bf16 padded 4096x800, and row sq-norms (f32)
__global__ void prep_x(const float* __restrict__ X, bf16* __restrict__ Xbf,
                       float* __restrict__ sqx) {
    const int row = blockIdx.x;
    const float* xr = X + (size_t)row * DH;
    bf16* xb = Xbf + (size_t)row * KX;
    float s = 0.f;
    for (int c = threadIdx.x; c < KX; c += 128) {
        float v = (c < DH) ? xr[c] : 0.f;
        xb[c] = __float2bfloat16(v);
        s += v * v;
    }
    #pragma unroll
    for (int off = 32; off; off >>= 1) s += __shfl_down(s, off, 64);
    __shared__ float ps[2];
    if ((threadIdx.x & 63) == 0) ps[threadIdx.x >> 6] = s;
    __syncthreads();
    if (threadIdx.x == 0) sqx[row] = ps[0] + ps[1];
}

// ---- prep: e_to (cols 0..15 of embed) -> bf16 4096x32 (upper 16 zero), sq-norms
__global__ void prep_e(const float* __restrict__ emb, bf16* __restrict__ Ebf,
                       float* __restrict__ sqe) {
    const int r = blockIdx.x * blockDim.x + threadIdx.x;
    if (r >= NB) return;
    const float* er = emb + (size_t)r * 32;
    bf16* eb = Ebf + (size_t)r * 32;
    float s = 0.f;
    #pragma unroll
    for (int c = 0; c < 16; ++c) {
        float v = er[c];
        eb[c] = __float2bfloat16(v);
        eb[16 + c] = __float2bfloat16(0.f);
        s += v * v;
    }
    sqe[r] = s;
}

// ---- UMAP CE loss: per-block partial sums (no atomics)
__global__ void umap_kernel(const float* __restrict__ emb, const int* __restrict__ perm,
                            float* __restrict__ upart) {
    const int t = blockIdx.x * 256 + threadIdx.x;
    float val = 0.f;
    if (t < NB) {
        const float* a = emb + (size_t)t * 32;
        float d2 = 0.f;
        #pragma unroll
        for (int c = 0; c < 16; ++c) { float df = a[c] - a[16 + c]; d2 += df * df; }
        float d = sqrtf(d2);
        float p = 1.f / (1.f + A_CONST * powf(d, PEXP));
        val = -logf(fminf(fmaxf(p, EPS_C), 1.f));
    } else if (t < NTOT) {
        const int k = t - NB;
        const int ti = k / 5;
        const int fi = perm[k] / 5;
        const float* a = emb + (size_t)ti * 32;
        const float* b = emb + (size_t)fi * 32 + 16;
        float d2 = 0.f;
        #pragma unroll
        for (int c = 0; c < 16; ++c) { float df = a[c] - b[c]; d2 += df * df; }
        float d = sqrtf(d2);
        float p = 1.f / (1.f + A_CONST * powf(d, PEXP));
        val = -logf(fminf(fmaxf(1.f - p, EPS_C), 1.f));
    }
    #pragma unroll
    for (int off = 32; off; off >>= 1) val += __shfl_down(val, off, 64);
    __shared__ float ps[4];
    if ((threadIdx.x & 63) == 0) ps[threadIdx.x >> 6] = val;
    __syncthreads();
    if (threadIdx.x == 0) upart[blockIdx.x] = ps[0] + ps[1] + ps[2] + ps[3];
}

// ---- main: 128x128 tile dual-gram (X-gram K=800, E-gram K=32) + fused stats epilogue
__global__ __launch_bounds__(256) void gram_kernel(
    const bf16* __restrict__ Xbf, const bf16* __restrict__ Ebf,
    const float* __restrict__ sqx, const float* __restrict__ sqe,
    float* __restrict__ statsp) {
    __shared__ bf16 As[128 * 32];   // 8 KB
    __shared__ bf16 Bs[128 * 32];   // 8 KB
    __shared__ float sqxs[256];     // [0..127]=i rows, [128..255]=j cols
    __shared__ float sqes[256];

    const int i0 = blockIdx.y * 128;
    const int j0 = blockIdx.x * 128;
    const int tid  = threadIdx.x;
    const int wave = tid >> 6;
    const int lane = tid & 63;
    const int wy = wave >> 1, wx = wave & 1;
    const int quad = lane >> 4, l15 = lane & 15;

    f32x4 acc[4][4];
    #pragma unroll
    for (int a = 0; a < 4; ++a)
        #pragma unroll
        for (int b = 0; b < 4; ++b)
            acc[a][b] = (f32x4){0.f, 0.f, 0.f, 0.f};

    // staging geometry: 8 chunks of 16 rows; wave stages chunks {2w, 2w+1};
    // lane L: row chunk*16 + (L>>2), 16B segment (L&3) within the 64B row-chunk.
    const int c0  = wave * 2;
    const int rA  = lane >> 2;
    const int seg = (lane & 3) * 8;

    for (int kk = 0; kk < KX; kk += 32) {
        __syncthreads();
        #pragma unroll
        for (int cc = 0; cc < 2; ++cc) {
            const int c = c0 + cc;
            gl2lds16(Xbf + (size_t)(i0 + c * 16 + rA) * KX + kk + seg, As + c * 512);
            gl2lds16(Xbf + (size_t)(j0 + c * 16 + rA) * KX + kk + seg, Bs + c * 512);
        }
        __syncthreads();
        bf16x8 af[4], bfr[4];
        #pragma unroll
        for (int mi = 0; mi < 4; ++mi)
            af[mi] = *(const bf16x8*)&As[(wy * 64 + mi * 16 + l15) * 32 + quad * 8];
        #pragma unroll
        for (int ni = 0; ni < 4; ++ni)
            bfr[ni] = *(const bf16x8*)&Bs[(wx * 64 + ni * 16 + l15) * 32 + quad * 8];
        #pragma unroll
        for (int mi = 0; mi < 4; ++mi)
            #pragma unroll
            for (int ni = 0; ni < 4; ++ni)
                acc[mi][ni] = __builtin_amdgcn_mfma_f32_16x16x32_bf16(
                    af[mi], bfr[ni], acc[mi][ni], 0, 0, 0);
    }

    // one extra K-iter for the low-dim (e_to) gram; rows are 64B = same geometry
    __syncthreads();
    #pragma unroll
    for (int cc = 0; cc < 2; ++cc) {
        const int c = c0 + cc;
        gl2lds16(Ebf + (size_t)(i0 + c * 16 + rA) * 32 + seg, As + c * 512);
        gl2lds16(Ebf + (size_t)(j0 + c * 16 + rA) * 32 + seg, Bs + c * 512);
    }
    if (tid < 128) {
        sqxs[tid] = sqx[i0 + tid]; sqxs[128 + tid] = sqx[j0 + tid];
        sqes[tid] = sqe[i0 + tid]; sqes[128 + tid] = sqe[j0 + tid];
    }
    __syncthreads();
    f32x4 accE[4][4];
    {
        bf16x8 af[4], bfr[4];
        #pragma unroll
        for (int mi = 0; mi < 4; ++mi)
            af[mi] = *(const bf16x8*)&As[(wy * 64 + mi * 16 + l15) * 32 + quad * 8];
        #pragma unroll
        for (int ni = 0; ni < 4; ++ni)
            bfr[ni] = *(const bf16x8*)&Bs[(wx * 64 + ni * 16 + l15) * 32 + quad * 8];
        #pragma unroll
        for (int mi = 0; mi < 4; ++mi)
            #pragma unroll
            for (int ni = 0; ni < 4; ++ni) {
                f32x4 z = (f32x4){0.f, 0.f, 0.f, 0.f};
                accE[mi][ni] = __builtin_amdgcn_mfma_f32_16x16x32_bf16(
                    af[mi], bfr[ni], z, 0, 0, 0);
            }
    }

    // Epilogue: H = high dist, L = low dist; per-row partial stats -> private slot.
    // C/D layout: col = lane&15, row = quad*4 + reg  [verified m89/m91]
    const int slot = blockIdx.x * 2 + wx;     // 64 slots per row, no collisions
    #pragma unroll
    for (int mi = 0; mi < 4; ++mi) {
        const int ilocb = wy * 64 + mi * 16 + quad * 4;
        float sH[4] = {0,0,0,0}, sH2[4] = {0,0,0,0}, sL[4] = {0,0,0,0},
              sL2[4] = {0,0,0,0}, sHL[4] = {0,0,0,0};
        #pragma unroll
        for (int ni = 0; ni < 4; ++ni) {
            const int jloc = wx * 64 + ni * 16 + l15;
            const int j = j0 + jloc;
            const float sqxj = sqxs[128 + jloc];
            const float sqej = sqes[128 + jloc];
            #pragma unroll
            for (int r = 0; r < 4; ++r) {
                const int iloc = ilocb + r;
                const int i = i0 + iloc;
                float H, L;
                if (i == j) { H = 0.f; L = 0.f; }
                else {
                    float d2  = sqxs[iloc] + sqxj - 2.0f * acc[mi][ni][r];
                    H = sqrtf(fmaxf(d2, 0.f));
                    float d2e = sqes[iloc] + sqej - 2.0f * accE[mi][ni][r];
                    L = sqrtf(fmaxf(d2e, 0.f));
                }
                sH[r] += H; sH2[r] += H * H; sL[r] += L; sL2[r] += L * L; sHL[r] += H * L;
            }
        }
        #pragma unroll
        for (int r = 0; r < 4; ++r) {
            float v0 = sH[r], v1 = sH2[r], v2 = sL[r], v3 = sL2[r], v4 = sHL[r];
            #pragma unroll
            for (int off = 1; off < 16; off <<= 1) {  // reduce across the 16-lane quad
                v0 += __shfl_xor(v0, off, 64);
                v1 += __shfl_xor(v1, off, 64);
                v2 += __shfl_xor(v2, off, 64);
                v3 += __shfl_xor(v3, off, 64);
                v4 += __shfl_xor(v4, off, 64);
            }
            if (l15 == 0) {
                const int i = i0 + ilocb + r;
                float* base = statsp + (size_t)slot * NB + i;   // [c][slot][i]
                base[0 * SLAB] = v0;
                base[1 * SLAB] = v1;
                base[2 * SLAB] = v2;
                base[3 * SLAB] = v3;
                base[4 * SLAB] = v4;
            }
        }
    }
}

// ---- finish1: reduce 64 slots per row, compute per-row corr contribution
__global__ void finish1_kernel(const float* __restrict__ statsp, float* __restrict__ cpart) {
    const int r = blockIdx.x * 256 + threadIdx.x;   // grid 16 x 256 = 4096 rows
    float sh = 0.f, sh2 = 0.f, sl = 0.f, sl2 = 0.f, shl = 0.f;
    #pragma unroll 8
    for (int s = 0; s < NSLOT; ++s) {
        const float* base = statsp + (size_t)s * NB + r;
        sh  += base[0 * SLAB];
        sh2 += base[1 * SLAB];
        sl  += base[2 * SLAB];
        sl2 += base[3 * SLAB];
        shl += base[4 * SLAB];
    }
    const float invN = 1.0f / (float)NB;
    float num = shl - sh * sl * invN;
    float vh  = fmaxf(sh2 - sh * sh * invN, 0.f);
    float vl  = fmaxf(sl2 - sl * sl * invN, 0.f);
    float den = sqrtf(vh) * sqrtf(vl);
    float local = num / den;
    #pragma unroll
    for (int off = 32; off; off >>= 1) local += __shfl_down(local, off, 64);
    __shared__ float ps[4];
    if ((threadIdx.x & 63) == 0) ps[threadIdx.x >> 6] = local;
    __syncthreads();
    if (threadIdx.x == 0) cpart[blockIdx.x] = ps[0] + ps[1] + ps[2] + ps[3];
}

// ---- final: combine corr partials (16) + umap partials (96) -> loss
__global__ void final_kernel(const float* __restrict__ cpart, const float* __restrict__ upart,
                             float* __restrict__ out) {
    const int t = threadIdx.x;   // 128 threads
    float c = (t < 16) ? cpart[t] : 0.f;
    float u = (t < 96) ? upart[t] : 0.f;
    #pragma unroll
    for (int off = 32; off; off >>= 1) {
        c += __shfl_down(c, off, 64);
        u += __shfl_down(u, off, 64);
    }
    __shared__ float pc[2], pu[2];
    if ((t & 63) == 0) { pc[t >> 6] = c; pu[t >> 6] = u; }
    __syncthreads();
    if (t == 0) {
        float corr = (pc[0] + pc[1]) / (float)NB;
        float loss_g = -corr;
        float loss_u = (pu[0] + pu[1]) / (float)NTOT;
        out[0] = ALPHA_C * loss_u + BETA_C * loss_g;
    }
}

extern "C" void kernel_launch(void* const* d_in, const int* in_sizes, int n_in,
                              void* d_out, int out_size, void* d_ws, size_t ws_size,
                              hipStream_t stream) {
    const float* emb  = (const float*)d_in[0];   // (4096, 32) f32
    const float* ph   = (const float*)d_in[1];   // (4096, 784) f32
    const int*   perm = (const int*)d_in[2];     // (20480,) i32
    float* out = (float*)d_out;

    char* ws = (char*)d_ws;
    bf16*  Xbf    = (bf16*) (ws + WS_XBF);
    bf16*  Ebf    = (bf16*) (ws + WS_EBF);
    float* sqx    = (float*)(ws + WS_SQX);
    float* sqe    = (float*)(ws + WS_SQE);
    float* statsp = (float*)(ws + WS_STATSP);
    float* upart  = (float*)(ws + WS_UPART);
    float* cpart  = (float*)(ws + WS_CPART);

    prep_x<<<NB, 128, 0, stream>>>(ph, Xbf, sqx);
    prep_e<<<NB / 256, 256, 0, stream>>>(emb, Ebf, sqe);
    umap_kernel<<<NTOT / 256, 256, 0, stream>>>(emb, perm, upart);
    gram_kernel<<<dim3(32, 32), 256, 0, stream>>>(Xbf, Ebf, sqx, sqe, statsp);
    finish1_kernel<<<16, 256, 0, stream>>>(statsp, cpart);
    final_kernel<<<1, 128, 0, stream>>>(cpart, upart, out);
}